// Round 13
// baseline (5432.672 us; speedup 1.0000x reference)
//
#include <hip/hip_runtime.h>

// ---------------------------------------------------------------------------
// VRAE LSTM: B=512, T=512, HE=HD=512, L=64.
// Round 13 = round-10 structure with the flags/drain/poll protocol replaced
// by gen-tagged h words validated PER-WORD with individual retry (r11's flood
// came from re-reading the whole tile per retry + blind prefetch). Stage of
// step t+1 overlaps ew of step t (tid>=256 race ahead); 2 barriers/step.
// Decoder heads wave-local (shfl) + one atomicAdd per row-slice, off-chain.
// 32 groups (16 rows) x 8 WGs (64 units, 512 thr). U packed f16, asm-loaded.
// ---------------------------------------------------------------------------

#define B_   512
#define T_   512
#define H_   512
#define NGR  32
#define WPG  8
#define RPG  16
#define UPW  64

typedef _Float16 f16;
typedef _Float16 f16x8 __attribute__((ext_vector_type(8)));
typedef float f32x16 __attribute__((ext_vector_type(16)));
typedef unsigned long long u64;
typedef unsigned int u32;

// d_out floats: mu_dec[512*512] | sg_dec[512*512] | mu_enc[512*64] | sg_enc[512*64]
#define OFF_SG_DEC 262144
#define OFF_MU_ENC 524288
#define OFF_SG_ENC 557056

__device__ __forceinline__ float sigm_(float x) { return 1.f / (1.f + __expf(-x)); }
__device__ __forceinline__ float tanh_(float x) {
  float t = fabsf(x);
  float e = __expf(2.f * t);
  float r = 1.f - 2.f / (e + 1.f);
  return x < 0.f ? -r : r;
}
__device__ __forceinline__ float softplus_(float x) {
  return fmaxf(x, 0.f) + log1pf(__expf(-fabsf(x)));
}
__device__ __forceinline__ int fresh_(u64 w, u32 g) {
  return ((u32)(w >> 48) == g) & (((u32)(w >> 16) & 0xffffu) == g);
}
__device__ __forceinline__ u32 packh_(u64 w) {
  return (u32)(w & 0xffffu) | (((u32)(w >> 32) & 0xffffu) << 16);
}

// ---------------------------------------------------------------------------
// Pack U [512][2048] f32 -> f16 fragment order.
// ---------------------------------------------------------------------------
__global__ void pack_U(const float* __restrict__ U, f16* __restrict__ Upk) {
  const int e = blockIdx.x * 256 + threadIdx.x;  // 2^20 elements exactly
  const int j = e & 7, lane = (e >> 3) & 63, ks = (e >> 9) & 31;
  const int w = (e >> 14) & 7, wg = (e >> 17) & 7;
  const int ccol = lane & 31, khalf = lane >> 5;
  const int uu = ccol >> 2, gate = ccol & 3;
  const int k = ks * 16 + khalf * 8 + j;
  const int gcol = gate * 512 + wg * UPW + w * 8 + uu;
  Upk[e] = (f16)U[k * 2048 + gcol];
}

// ---------------------------------------------------------------------------
// IS_DEC=0: xin=[B][T] input (LDS-staged once), wa=enc_W, wb=enc_b
// IS_DEC=1: xin=zin [B][2048] incl bias, wa=dmu_W, wb=dstd_W
// hbuf: u32 [2][512][512] gen-tagged h (gen16|f16), shared enc/dec
// (enc tags 1..512; dec tags 0x8000..0x8200 — disjoint, no clearing needed).
// ---------------------------------------------------------------------------
template <int IS_DEC>
__global__ void __launch_bounds__(512, 1)
lstm_rec(const f16* __restrict__ Upk,
         const float* __restrict__ xin,
         const float* __restrict__ wa,
         const float* __restrict__ wb,
         u32* __restrict__ hbuf,
         float* __restrict__ accmu,
         float* __restrict__ accsg) {
  const int bid = blockIdx.x;
  const int wg = (bid >> 3) & 7;             // unit slice 0..7
  const int g = (bid & 7) * 4 + (bid >> 6);  // group 0..31 (XCD-local WGs)
  const int tid = threadIdx.x;
  const int wave = tid >> 6, lane = tid & 63;
  const int R0 = g * RPG;
  const int U0 = wg * UPW;
  const u32 GB = IS_DEC ? 0x8000u : 0u;

  // ---- Breg from packed U: asm loads (non-remat, resident) ----------------
  const int ccol = lane & 31, khalf = lane >> 5;
  f16x8 Breg[32];
#pragma unroll
  for (int ks = 0; ks < 32; ++ks) {
    const f16* p = Upk + (((wg * 8 + wave) * 32 + ks) << 9) + lane * 8;
    asm volatile("global_load_dwordx4 %0, %1, off\n\ts_waitcnt vmcnt(0)"
                 : "=v"(Breg[ks]) : "v"(p));
  }

  // ---- per-thread elementwise mapping (tid<256 active) --------------------
  const int row = tid >> 4;        // 0..15
  const int q = (tid & 15) * 4;    // first of 4 units
  float addv[16], xw[16], dmur[4], dstdr[4];
  if (tid < 256) {
#pragma unroll
    for (int m = 0; m < 4; ++m) {
#pragma unroll
      for (int gt = 0; gt < 4; ++gt) {
        const int col = gt * 512 + U0 + q + m;
        if (IS_DEC) {
          addv[m * 4 + gt] = xin[(R0 + row) * 2048 + col];
          xw[m * 4 + gt] = 0.f;
        } else {
          addv[m * 4 + gt] = wb[col];
          xw[m * 4 + gt] = wa[col];
        }
      }
      if (IS_DEC) {
        dmur[m] = wa[U0 + q + m];
        dstdr[m] = wb[U0 + q + m];
      } else {
        dmur[m] = 0.f;
        dstdr[m] = 0.f;
      }
    }
  }

  float cst[4] = {0.f, 0.f, 0.f, 0.f};

  __shared__ __align__(16) f16 hstage[RPG * 536];   // 17,152 B
  __shared__ float gatesLds[RPG * 260];             // 16,640 B
  __shared__ float xl[RPG * 516];                   // 33,024 B (encoder x)

  if (!IS_DEC) {
#pragma unroll
    for (int i = 0; i < 16; ++i) {
      const int idx = tid + i * 512;
      const int r = idx >> 9, c2 = idx & 511;
      xl[r * 516 + c2] = xin[(R0 + r) * T_ + c2];
    }
    __syncthreads();
  }

  // staging: 8 u64/thread of the [16 rows][256 u64] tagged tile
  int srow[8], scol[8], gidx[8];
#pragma unroll
  for (int i = 0; i < 8; ++i) {
    const int w = tid + i * 512;
    srow[i] = w >> 8; scol[i] = w & 255;
    gidx[i] = (R0 + srow[i]) * 256 + scol[i];
  }
  const u64* hb64 = (const u64*)hbuf;
  const int hrow = lane & 15;  // MFMA A row

  for (int t = 0; t < T_; ++t) {
    const int b0 = (t & 1) * 131072;          // u64 offset, read buffer
    const int c1 = ((t + 1) & 1) * 262144;    // u32 offset, write buffer
    const u32 gr = GB + (u32)t, gn = gr + 1u;

    // ---- stage: batch-issue 8 loads, then validate per word w/ retry ----
    u64 v[8];
#pragma unroll
    for (int i = 0; i < 8; ++i)
      v[i] = __hip_atomic_load(hb64 + b0 + gidx[i], __ATOMIC_RELAXED,
                               __HIP_MEMORY_SCOPE_AGENT);
#pragma unroll
    for (int i = 0; i < 8; ++i) {
      u64 w = v[i];
      while (!fresh_(w, gr))
        w = __hip_atomic_load(hb64 + b0 + gidx[i], __ATOMIC_RELAXED,
                              __HIP_MEMORY_SCOPE_AGENT);
      *(u32*)&hstage[srow[i] * 536 + scol[i] * 2] = packh_(w);
    }
    __syncthreads();  // BAR1: hstage ready

    // ---- gates = h @ U (MFMA 32x32x16, B in regs) ----
    f32x16 acc;
#pragma unroll
    for (int j = 0; j < 16; ++j) acc[j] = 0.f;
#pragma unroll
    for (int ks = 0; ks < 32; ++ks) {
      f16x8 a = *(const f16x8*)&hstage[hrow * 536 + ks * 16 + khalf * 8];
      acc = __builtin_amdgcn_mfma_f32_32x32x16_f16(a, Breg[ks], acc, 0, 0, 0);
    }
#pragma unroll
    for (int r = 0; r < 8; ++r) {
      const int orow = (r & 3) + 8 * (r >> 2) + 4 * khalf;
      gatesLds[orow * 260 + wave * 32 + ccol] = acc[r];
    }
    __syncthreads();  // BAR2: gates ready; tid>=256 may now stage t+1

    // ---- elementwise LSTM update + tagged store (tid<256) ----
    if (tid < 256) {
      float xv = 0.f;
      if (!IS_DEC) xv = xl[row * 516 + t];
      float hn[4];
#pragma unroll
      for (int m = 0; m < 4; ++m) {
        float ga[4];
#pragma unroll
        for (int gt = 0; gt < 4; ++gt) {
          float vg = gatesLds[row * 260 + (q + m) * 4 + gt] + addv[m * 4 + gt];
          if (!IS_DEC) vg += xv * xw[m * 4 + gt];
          ga[gt] = vg;
        }
        const float iv = sigm_(ga[0]);
        const float fv = sigm_(ga[1]);
        const float gv = tanh_(ga[2]);
        const float ov = sigm_(ga[3]);
        const float cn = fv * cst[m] + iv * gv;
        cst[m] = cn;
        hn[m] = ov * tanh_(cn);
      }
      union { f16 h; unsigned short u; } h0_, h1_, h2_, h3_;
      h0_.h = (f16)hn[0]; h1_.h = (f16)hn[1];
      h2_.h = (f16)hn[2]; h3_.h = (f16)hn[3];
      const u64 tg = (u64)gn << 16;
      const u64 w0 = (tg | h0_.u) | ((tg | h1_.u) << 32);
      const u64 w1 = (tg | h2_.u) | ((tg | h3_.u) << 32);
      u64* hdst = (u64*)(hbuf + c1 + (R0 + row) * 512 + U0 + q);
      __hip_atomic_store(hdst, w0, __ATOMIC_RELAXED, __HIP_MEMORY_SCOPE_AGENT);
      __hip_atomic_store(hdst + 1, w1, __ATOMIC_RELAXED, __HIP_MEMORY_SCOPE_AGENT);

      // ---- decoder heads, wave-local (16 writers of a row share a wave) ----
      if (IS_DEC) {
        float pmu = 0.f, psg = 0.f;
#pragma unroll
        for (int m = 0; m < 4; ++m) {
          pmu += (float)((f16)hn[m]) * dmur[m];
          psg += (float)((f16)hn[m]) * dstdr[m];
        }
#pragma unroll
        for (int o = 1; o < 16; o <<= 1) {
          pmu += __shfl_xor(pmu, o);
          psg += __shfl_xor(psg, o);
        }
        if ((tid & 15) == 0) {
          unsafeAtomicAdd(&accmu[(R0 + row) * T_ + t], pmu);
          unsafeAtomicAdd(&accsg[(R0 + row) * T_ + t], psg);
        }
      }
    }
    // no release barrier: BAR1 of step t+1 is the join.
  }
}

// ---------------------------------------------------------------------------
__global__ void enc_heads(const u32* __restrict__ h0, const float* __restrict__ emuW,
                          const float* __restrict__ emub, const float* __restrict__ estdW,
                          const float* __restrict__ estdb, float* __restrict__ out,
                          float* __restrict__ z) {
  const int b = blockIdx.x, tid = threadIdx.x;
  __shared__ float hrow[512];
  for (int k = tid; k < 512; k += 128) {
    union { unsigned short u; f16 h; } c;
    c.u = (unsigned short)(h0[b * 512 + k] & 0xffffu);
    hrow[k] = (float)c.h;
  }
  __syncthreads();
  const int head = tid >> 6, l = tid & 63;
  const float* W = head ? estdW : emuW;
  float a = 0.f;
#pragma unroll 8
  for (int k = 0; k < 512; ++k) a += hrow[k] * W[k * 64 + l];
  if (head == 0) {
    const float v = a + emub[l];
    out[OFF_MU_ENC + b * 64 + l] = v;
    z[b * 64 + l] = v;
  } else {
    out[OFF_SG_ENC + b * 64 + l] = softplus_(a + estdb[l]);
  }
}

// ---------------------------------------------------------------------------
// Decoder prep: hd = tanh(z@dfs_W+dfs_b) -> hbuf buf0 (gen 0x8000);
//               zin = z@dec_W+dec_b
// ---------------------------------------------------------------------------
__global__ void dec_prep(const float* __restrict__ z, const float* __restrict__ dfsW,
                         const float* __restrict__ dfsb, const float* __restrict__ decW,
                         const float* __restrict__ decb, u32* __restrict__ hbuf,
                         float* __restrict__ zin) {
  const int b = blockIdx.x, tid = threadIdx.x;
  __shared__ float zl[64];
  if (tid < 64) zl[tid] = z[b * 64 + tid];
  __syncthreads();
  for (int c = tid; c < 512; c += 256) {
    float a = dfsb[c];
#pragma unroll
    for (int l = 0; l < 64; ++l) a += zl[l] * dfsW[l * 512 + c];
    union { f16 h; unsigned short u; } hc; hc.h = (f16)tanh_(a);
    hbuf[b * 512 + c] = (0x8000u << 16) | (u32)hc.u;
  }
  for (int c = tid; c < 2048; c += 256) {
    float a = decb[c];
#pragma unroll
    for (int l = 0; l < 64; ++l) a += zl[l] * decW[l * 2048 + c];
    zin[b * 2048 + c] = a;
  }
}

// ---------------------------------------------------------------------------
__global__ void finalize_k(const float* __restrict__ accmu, const float* __restrict__ accsg,
                           const float* __restrict__ dmub, const float* __restrict__ dstdb,
                           float* __restrict__ out) {
  const int i = blockIdx.x * 256 + threadIdx.x;
  out[i] = accmu[i] + dmub[0];
  out[OFF_SG_DEC + i] = softplus_(accsg[i] + dstdb[0]);
}

// ---------------------------------------------------------------------------
extern "C" void kernel_launch(void* const* d_in, const int* in_sizes, int n_in,
                              void* d_out, int out_size, void* d_ws, size_t ws_size,
                              hipStream_t stream) {
  (void)in_sizes; (void)n_in; (void)out_size; (void)ws_size;
  const float* x     = (const float*)d_in[0];
  const float* encW  = (const float*)d_in[1];
  const float* encU  = (const float*)d_in[2];
  const float* encb  = (const float*)d_in[3];
  const float* emuW  = (const float*)d_in[4];
  const float* emub  = (const float*)d_in[5];
  const float* estdW = (const float*)d_in[6];
  const float* estdb = (const float*)d_in[7];
  const float* dfsW  = (const float*)d_in[8];
  const float* dfsb  = (const float*)d_in[9];
  const float* decW  = (const float*)d_in[10];
  const float* decU  = (const float*)d_in[11];
  const float* decb  = (const float*)d_in[12];
  const float* dmuW  = (const float*)d_in[13];
  const float* dmub  = (const float*)d_in[14];
  const float* dstdW = (const float*)d_in[15];
  const float* dstdb = (const float*)d_in[16];

  char* ws = (char*)d_ws;
  u32*   hbuf  = (u32*)(ws + 0);                   // 2 MB: [2][512][512] u32
  float* accmu = (float*)(ws + (2u << 20));        // 1 MB
  float* accsg = (float*)(ws + (3u << 20));        // 1 MB
  f16*   UpkE  = (f16*)(ws + (4u << 20));          // 2 MB (dead after encoder)
  float* zin   = (float*)(ws + (4u << 20));        // 4 MB (overlays UpkE)
  f16*   UpkD  = (f16*)(ws + (8u << 20));          // 2 MB
  float* z     = (float*)(ws + (10u << 20));       // 128 KB
  float* out   = (float*)d_out;

  // zero hbuf (gen tags) + head accumulators every launch
  hipMemsetAsync(d_ws, 0, 4u << 20, stream);

  hipLaunchKernelGGL(pack_U, dim3(4096), dim3(256), 0, stream, encU, UpkE);
  hipLaunchKernelGGL(pack_U, dim3(4096), dim3(256), 0, stream, decU, UpkD);

  hipLaunchKernelGGL((lstm_rec<0>), dim3(256), dim3(512), 0, stream,
                     UpkE, x, encW, encb, hbuf, (float*)nullptr, (float*)nullptr);
  hipLaunchKernelGGL(enc_heads, dim3(512), dim3(128), 0, stream,
                     hbuf, emuW, emub, estdW, estdb, out, z);
  hipLaunchKernelGGL(dec_prep, dim3(512), dim3(256), 0, stream,
                     z, dfsW, dfsb, decW, decb, hbuf, zin);
  hipLaunchKernelGGL((lstm_rec<1>), dim3(256), dim3(512), 0, stream,
                     UpkD, zin, dmuW, dstdW, hbuf, accmu, accsg);
  hipLaunchKernelGGL(finalize_k, dim3(1024), dim3(256), 0, stream,
                     accmu, accsg, dmub, dstdb, out);
}

// Round 14
// 4403.414 us; speedup vs baseline: 1.2337x; 1.2337x over previous
//
#include <hip/hip_runtime.h>

// ---------------------------------------------------------------------------
// VRAE LSTM: B=512, T=512, HE=HD=512, L=64.
// Round 14 = round-10 (best measured, 4.23ms) with two protocol trims:
// (a) per-wave flag polling at loop top (+__all) -> one fewer barrier/step,
//     stage loads issue per-wave immediately after readiness;
// (b) decoder heads wave-local via shfl (no pmu/psg LDS), after flag store.
// Flags+drain protocol with compact f16 h kept (gen-tag abandoned: 2x bytes).
// 32 groups (16 rows) x 8 WGs (64 units, 512 thr). U packed f16, asm-loaded.
// ---------------------------------------------------------------------------

#define B_   512
#define T_   512
#define H_   512
#define NGR  32
#define WPG  8
#define RPG  16
#define UPW  64

typedef _Float16 f16;
typedef _Float16 f16x8 __attribute__((ext_vector_type(8)));
typedef _Float16 f16x4 __attribute__((ext_vector_type(4)));
typedef float f32x16 __attribute__((ext_vector_type(16)));
typedef unsigned long long u64;

// d_out floats: mu_dec[512*512] | sg_dec[512*512] | mu_enc[512*64] | sg_enc[512*64]
#define OFF_SG_DEC 262144
#define OFF_MU_ENC 524288
#define OFF_SG_ENC 557056

__device__ __forceinline__ float sigm_(float x) { return 1.f / (1.f + __expf(-x)); }
__device__ __forceinline__ float tanh_(float x) {
  float t = fabsf(x);
  float e = __expf(2.f * t);
  float r = 1.f - 2.f / (e + 1.f);
  return x < 0.f ? -r : r;
}
__device__ __forceinline__ float softplus_(float x) {
  return fmaxf(x, 0.f) + log1pf(__expf(-fabsf(x)));
}

// ---------------------------------------------------------------------------
// Pack U [512][2048] f32 -> f16 fragment order.
// ---------------------------------------------------------------------------
__global__ void pack_U(const float* __restrict__ U, f16* __restrict__ Upk) {
  const int e = blockIdx.x * 256 + threadIdx.x;  // 2^20 elements exactly
  const int j = e & 7, lane = (e >> 3) & 63, ks = (e >> 9) & 31;
  const int w = (e >> 14) & 7, wg = (e >> 17) & 7;
  const int ccol = lane & 31, khalf = lane >> 5;
  const int uu = ccol >> 2, gate = ccol & 3;
  const int k = ks * 16 + khalf * 8 + j;
  const int gcol = gate * 512 + wg * UPW + w * 8 + uu;
  Upk[e] = (f16)U[k * 2048 + gcol];
}

// ---------------------------------------------------------------------------
// IS_DEC=0: xin=[B][T] input (LDS-staged once), wa=enc_W, wb=enc_b
// IS_DEC=1: xin=zin [B][2048] incl bias, wa=dmu_W, wb=dstd_W
// hbuf: [2][512][512] f16 double-buffered h; flags: [32 g][8 wg][32 ints]
// ---------------------------------------------------------------------------
template <int IS_DEC>
__global__ void __launch_bounds__(512, 1)
lstm_rec(const f16* __restrict__ Upk,
         const float* __restrict__ xin,
         const float* __restrict__ wa,
         const float* __restrict__ wb,
         f16* __restrict__ hbuf,
         float* __restrict__ accmu,
         float* __restrict__ accsg,
         int* __restrict__ flags) {
  const int bid = blockIdx.x;
  // XCD-local: a group's 8 WGs share bid%8 -> one XCD.
  const int wg = (bid >> 3) & 7;
  const int g = (bid & 7) * 4 + (bid >> 6);  // 0..31
  const int tid = threadIdx.x;
  const int wave = tid >> 6, lane = tid & 63;
  const int R0 = g * RPG;
  const int U0 = wg * UPW;

  // ---- Breg from packed U: asm loads (non-remat, resident) ----------------
  const int ccol = lane & 31, khalf = lane >> 5;
  f16x8 Breg[32];
#pragma unroll
  for (int ks = 0; ks < 32; ++ks) {
    const f16* p = Upk + (((wg * 8 + wave) * 32 + ks) << 9) + lane * 8;
    asm volatile("global_load_dwordx4 %0, %1, off\n\ts_waitcnt vmcnt(0)"
                 : "=v"(Breg[ks]) : "v"(p));
  }

  // ---- per-thread elementwise mapping (tid<256 active) --------------------
  const int row = tid >> 4;        // 0..15
  const int q = (tid & 15) * 4;    // first of 4 units
  float addv[16], xw[16], dmur[4], dstdr[4];
  if (tid < 256) {
#pragma unroll
    for (int m = 0; m < 4; ++m) {
#pragma unroll
      for (int gt = 0; gt < 4; ++gt) {
        const int col = gt * 512 + U0 + q + m;
        if (IS_DEC) {
          addv[m * 4 + gt] = xin[(R0 + row) * 2048 + col];
          xw[m * 4 + gt] = 0.f;
        } else {
          addv[m * 4 + gt] = wb[col];
          xw[m * 4 + gt] = wa[col];
        }
      }
      if (IS_DEC) {
        dmur[m] = wa[U0 + q + m];
        dstdr[m] = wb[U0 + q + m];
      } else {
        dmur[m] = 0.f;
        dstdr[m] = 0.f;
      }
    }
  }

  float cst[4] = {0.f, 0.f, 0.f, 0.f};

  __shared__ __align__(16) f16 hstage[RPG * 536];   // 17,152 B
  __shared__ float gatesLds[RPG * 260];             // 16,640 B
  __shared__ float xl[RPG * 516];                   // 33,024 B (encoder x)

  if (!IS_DEC) {
    // one-time coalesced stage of x[R0..R0+16)[0..512) -> LDS
#pragma unroll
    for (int i = 0; i < 16; ++i) {
      const int idx = tid + i * 512;
      const int r = idx >> 9, c2 = idx & 511;
      xl[r * 516 + c2] = xin[(R0 + r) * T_ + c2];
    }
    __syncthreads();
  }

  const int hrow = lane & 15;  // MFMA A row
  int* const myflag = &flags[(g * WPG + wg) * 32];
  int* const grpflags = &flags[(g * WPG) * 32];

  for (int t = 0; t < T_; ++t) {
    // ------------------ per-wave poll: h(t) ready? -----------------------
    // flag[wg] == number of completed steps by that WG (h(t) stored+drained
    // before flag t). Step t needs all flags >= t. t=0: initial h ready.
    if (t) {
      for (;;) {
        int fv = t;
        if (lane < WPG)
          fv = __hip_atomic_load(&grpflags[lane * 32], __ATOMIC_RELAXED,
                                 __HIP_MEMORY_SCOPE_AGENT);
        if (__all(fv >= t)) break;
        asm volatile("s_sleep 1");
      }
    }

    // ------------------ stage group h tile (16KB) -> LDS -----------------
    const u64* hsrc64 = (const u64*)(hbuf + (t & 1) * (B_ * H_) + R0 * H_);
#pragma unroll
    for (int i = 0; i < 4; ++i) {
      const int w = tid + i * 512;  // 2048 u64 total; 128 u64 per row
      const int r = w >> 7, c8 = w & 127;
      u64 v = __hip_atomic_load(hsrc64 + w, __ATOMIC_RELAXED,
                                __HIP_MEMORY_SCOPE_AGENT);
      *(u64*)&hstage[r * 536 + c8 * 4] = v;
    }
    __syncthreads();  // BAR1: hstage ready

    // ------------------ gates = h @ U (MFMA 32x32x16, B in regs) ---------
    f32x16 acc;
#pragma unroll
    for (int j = 0; j < 16; ++j) acc[j] = 0.f;
#pragma unroll
    for (int ks = 0; ks < 32; ++ks) {
      f16x8 a = *(const f16x8*)&hstage[hrow * 536 + ks * 16 + khalf * 8];
      acc = __builtin_amdgcn_mfma_f32_32x32x16_f16(a, Breg[ks], acc, 0, 0, 0);
    }
    // C rows 0..15 live in regs 0..7 (row=(r&3)+8*(r>>2)+4*khalf)
#pragma unroll
    for (int r = 0; r < 8; ++r) {
      const int orow = (r & 3) + 8 * (r >> 2) + 4 * khalf;
      gatesLds[orow * 260 + wave * 32 + ccol] = acc[r];
    }
    __syncthreads();  // BAR2: gates ready

    // ------------------ elementwise LSTM update (tid<256) ----------------
    float hn[4];
    if (tid < 256) {
      float xv = 0.f;
      if (!IS_DEC) xv = xl[row * 516 + t];
#pragma unroll
      for (int m = 0; m < 4; ++m) {
        float ga[4];
#pragma unroll
        for (int gt = 0; gt < 4; ++gt) {
          float v = gatesLds[row * 260 + (q + m) * 4 + gt] + addv[m * 4 + gt];
          if (!IS_DEC) v += xv * xw[m * 4 + gt];
          ga[gt] = v;
        }
        const float iv = sigm_(ga[0]);
        const float fv = sigm_(ga[1]);
        const float gv = tanh_(ga[2]);
        const float ov = sigm_(ga[3]);
        const float cn = fv * cst[m] + iv * gv;
        cst[m] = cn;
        hn[m] = ov * tanh_(cn);
      }
      union { f16x4 h4; u64 u; } cv;
#pragma unroll
      for (int m = 0; m < 4; ++m) cv.h4[m] = (f16)hn[m];
      f16* hdst = hbuf + ((t + 1) & 1) * (B_ * H_) + (R0 + row) * H_ + U0 + q;
      __hip_atomic_store((u64*)hdst, cv.u, __ATOMIC_RELAXED,
                         __HIP_MEMORY_SCOPE_AGENT);
    }

    // ------------------ release: h stores acked at LLC, then flag --------
    asm volatile("s_waitcnt vmcnt(0)" ::: "memory");
    __syncthreads();  // BAR3: all WG stores drained; hstage/gates reusable
    if (t + 1 < T_ && tid == 0)
      __hip_atomic_store(myflag, t + 1, __ATOMIC_RELAXED,
                         __HIP_MEMORY_SCOPE_AGENT);

    // ------------------ decoder heads (off-chain, wave-local) ------------
    if (IS_DEC && tid < 256) {
      float pmu = 0.f, psg = 0.f;
#pragma unroll
      for (int m = 0; m < 4; ++m) {
        pmu += (float)((f16)hn[m]) * dmur[m];
        psg += (float)((f16)hn[m]) * dstdr[m];
      }
#pragma unroll
      for (int o = 1; o < 16; o <<= 1) {
        pmu += __shfl_xor(pmu, o);
        psg += __shfl_xor(psg, o);
      }
      if ((tid & 15) == 0) {
        unsafeAtomicAdd(&accmu[(R0 + row) * T_ + t], pmu);
        unsafeAtomicAdd(&accsg[(R0 + row) * T_ + t], psg);
      }
    }
  }
}

// ---------------------------------------------------------------------------
__global__ void enc_heads(const f16* __restrict__ h0, const float* __restrict__ emuW,
                          const float* __restrict__ emub, const float* __restrict__ estdW,
                          const float* __restrict__ estdb, float* __restrict__ out,
                          float* __restrict__ z) {
  const int b = blockIdx.x, tid = threadIdx.x;
  __shared__ float hrow[512];
  for (int k = tid; k < 512; k += 128)
    hrow[k] = (float)h0[b * H_ + k];
  __syncthreads();
  const int head = tid >> 6, l = tid & 63;
  const float* W = head ? estdW : emuW;
  float a = 0.f;
#pragma unroll 8
  for (int k = 0; k < 512; ++k) a += hrow[k] * W[k * 64 + l];
  if (head == 0) {
    const float v = a + emub[l];
    out[OFF_MU_ENC + b * 64 + l] = v;
    z[b * 64 + l] = v;
  } else {
    out[OFF_SG_ENC + b * 64 + l] = softplus_(a + estdb[l]);
  }
}

// ---------------------------------------------------------------------------
__global__ void dec_prep(const float* __restrict__ z, const float* __restrict__ dfsW,
                         const float* __restrict__ dfsb, const float* __restrict__ decW,
                         const float* __restrict__ decb, f16* __restrict__ hbuf,
                         float* __restrict__ zin) {
  const int b = blockIdx.x, tid = threadIdx.x;
  __shared__ float zl[64];
  if (tid < 64) zl[tid] = z[b * 64 + tid];
  __syncthreads();
  for (int c = tid; c < 512; c += 256) {
    float a = dfsb[c];
#pragma unroll
    for (int l = 0; l < 64; ++l) a += zl[l] * dfsW[l * 512 + c];
    hbuf[b * H_ + c] = (f16)tanh_(a);
  }
  for (int c = tid; c < 2048; c += 256) {
    float a = decb[c];
#pragma unroll
    for (int l = 0; l < 64; ++l) a += zl[l] * decW[l * 2048 + c];
    zin[b * 2048 + c] = a;
  }
}

// ---------------------------------------------------------------------------
__global__ void finalize_k(const float* __restrict__ accmu, const float* __restrict__ accsg,
                           const float* __restrict__ dmub, const float* __restrict__ dstdb,
                           float* __restrict__ out) {
  const int i = blockIdx.x * 256 + threadIdx.x;
  out[i] = accmu[i] + dmub[0];
  out[OFF_SG_DEC + i] = softplus_(accsg[i] + dstdb[0]);
}

// ---------------------------------------------------------------------------
extern "C" void kernel_launch(void* const* d_in, const int* in_sizes, int n_in,
                              void* d_out, int out_size, void* d_ws, size_t ws_size,
                              hipStream_t stream) {
  (void)in_sizes; (void)n_in; (void)out_size; (void)ws_size;
  const float* x     = (const float*)d_in[0];
  const float* encW  = (const float*)d_in[1];
  const float* encU  = (const float*)d_in[2];
  const float* encb  = (const float*)d_in[3];
  const float* emuW  = (const float*)d_in[4];
  const float* emub  = (const float*)d_in[5];
  const float* estdW = (const float*)d_in[6];
  const float* estdb = (const float*)d_in[7];
  const float* dfsW  = (const float*)d_in[8];
  const float* dfsb  = (const float*)d_in[9];
  const float* decW  = (const float*)d_in[10];
  const float* decU  = (const float*)d_in[11];
  const float* decb  = (const float*)d_in[12];
  const float* dmuW  = (const float*)d_in[13];
  const float* dmub  = (const float*)d_in[14];
  const float* dstdW = (const float*)d_in[15];
  const float* dstdb = (const float*)d_in[16];

  char* ws = (char*)d_ws;
  f16* hbuf    = (f16*)(ws + 0);                        // 1 MB [2][512][512]
  float* accmu = (float*)(ws + (1u << 20));             // 1 MB
  float* accsg = (float*)(ws + (2u << 20));             // 1 MB
  int* flags   = (int*)(ws + (3u << 20));               // 64 KB (2 phases)
  f16* UpkE    = (f16*)(ws + (3u << 20) + 65536);       // 2 MB (dead post-enc)
  float* zin   = (float*)(ws + (3u << 20) + 65536);     // 4 MB (overlays UpkE)
  f16* UpkD    = (f16*)(ws + (7u << 20) + 65536);       // 2 MB
  float* z     = (float*)(ws + (9u << 20) + 65536);     // 128 KB
  float* out   = (float*)d_out;

  // zero hbuf/acc/flags (must be re-done every launch)
  hipMemsetAsync(d_ws, 0, (3u << 20) + 65536, stream);

  hipLaunchKernelGGL(pack_U, dim3(4096), dim3(256), 0, stream, encU, UpkE);
  hipLaunchKernelGGL(pack_U, dim3(4096), dim3(256), 0, stream, decU, UpkD);

  hipLaunchKernelGGL((lstm_rec<0>), dim3(256), dim3(512), 0, stream,
                     UpkE, x, encW, encb, hbuf, (float*)nullptr, (float*)nullptr,
                     flags);
  hipLaunchKernelGGL(enc_heads, dim3(512), dim3(128), 0, stream,
                     hbuf, emuW, emub, estdW, estdb, out, z);
  hipLaunchKernelGGL(dec_prep, dim3(512), dim3(256), 0, stream,
                     z, dfsW, dfsb, decW, decb, hbuf, zin);
  hipLaunchKernelGGL((lstm_rec<1>), dim3(256), dim3(512), 0, stream,
                     UpkD, zin, dmuW, dstdW, hbuf, accmu, accsg, flags + 8192);
  hipLaunchKernelGGL(finalize_k, dim3(1024), dim3(256), 0, stream,
                     accmu, accsg, dmub, dstdb, out);
}